// Round 7
// baseline (964.978 us; speedup 1.0000x reference)
//
#include <hip/hip_runtime.h>
#include <hip/hip_bf16.h>

// QuantizedLinear: y[M,N] = x[M,K] . W[N,K]^T + bias ; W = int4 * groupscale(G=128)
// Round 6: R5's 8-phase schedule de-lockstepped. 8 barriers/iter (6 end + 2
// publish), reads >=1-phase lead (B+Aq0 at publish phase post-MFMA, Aq1 at
// phase bottom), WAITV(4) counted publishes. Register-neutral vs R5.

typedef __bf16 bf16_t;
typedef __bf16 bf16x8 __attribute__((ext_vector_type(8)));
typedef float f32x4 __attribute__((ext_vector_type(4)));
typedef __attribute__((address_space(3))) unsigned char lds_byte;
typedef __attribute__((address_space(1))) unsigned char gmem_byte;

// ---------------- pre-pass 1: x fp32 -> bf16 ----------------
__global__ void cvt_x_kernel(const float* __restrict__ x, bf16_t* __restrict__ xb, long n8) {
  const long stride = (long)gridDim.x * blockDim.x;
  for (long i = (long)blockIdx.x * blockDim.x + threadIdx.x; i < n8; i += stride) {
    const float4* p = reinterpret_cast<const float4*>(x + i * 8);
    const float4 f0 = p[0];
    const float4 f1 = p[1];
    bf16x8 o;
    o[0] = (bf16_t)f0.x; o[1] = (bf16_t)f0.y; o[2] = (bf16_t)f0.z; o[3] = (bf16_t)f0.w;
    o[4] = (bf16_t)f1.x; o[5] = (bf16_t)f1.y; o[6] = (bf16_t)f1.z; o[7] = (bf16_t)f1.w;
    *reinterpret_cast<bf16x8*>(xb + i * 8) = o;
  }
}

// ---------------- pre-pass 2: W int32(int4) * scale -> bf16 ----------------
__global__ void deq_w_kernel(const int* __restrict__ qw, const float* __restrict__ sc,
                             bf16_t* __restrict__ wb, int I, int G) {
  const int n = blockIdx.y;
  const int kb = blockIdx.x * blockDim.x + threadIdx.x;
  const int k = kb * 8;
  if (k >= I) return;
  const float s = sc[(size_t)n * (I / G) + k / G];
  const int4* qp = reinterpret_cast<const int4*>(qw + (size_t)n * I + k);
  const int4 q0 = qp[0];
  const int4 q1 = qp[1];
  bf16x8 o;
  o[0] = (bf16_t)((float)q0.x * s);
  o[1] = (bf16_t)((float)q0.y * s);
  o[2] = (bf16_t)((float)q0.z * s);
  o[3] = (bf16_t)((float)q0.w * s);
  o[4] = (bf16_t)((float)q1.x * s);
  o[5] = (bf16_t)((float)q1.y * s);
  o[6] = (bf16_t)((float)q1.z * s);
  o[7] = (bf16_t)((float)q1.w * s);
  *reinterpret_cast<bf16x8*>(wb + (size_t)n * I + k) = o;
}

// =================== 256x256 8-wave 8-phase GEMM ===================
// LDS 128KB: dbuf d0 @0 / d1 @+64K; halves A0(+0) A1(+16K) B0(+32K) B1(+48K).
// Half = 128 rows x 64 k bf16, 128B rows; XOR swizzle 16B-slot ^= (row&7)
// (write: linear LDS dest + pre-permuted global source col; read: lane-const).
// Stage slots/iter(t,t+1): p1:d1.A1(t+1) p2:d0.B0(t+2) p3:d0.B1(t+2)
//   p4*:d0.A0(t+2) p5:d0.A1(t+2) p6:d1.B0(t+3) p7:d1.B1(t+3) p8*:d1.A0(t+3)
//   (* = post-publish-BAR).
// Reads: p2-bot: Aq1(d0); p4-mid(post-MFMA): B both(d1)+Aq0(d1);
//   p6-bot: Aq1(d1); p8-mid: B both(d0,t+2)+Aq0(d0,t+2). All >=1 phase lead.
// Publishes: WAITV(4)@p4 drains {p6',p7',p8',p1} = d1(t+1); WAITV(4)@p8
//   drains {p2..p5} = d0(t+2); never 0 in main loop. Carry = 6.
// WAR: each STG issues >= 1 barrier after its slot's last read drained
//   (reader WAITL -> reader end-BAR -> writer STG), audited per half.

#define WAITV(n) asm volatile("s_waitcnt vmcnt(" #n ")" ::: "memory")
#define WAITL(n) asm volatile("s_waitcnt lgkmcnt(" #n ")" ::: "memory")
#define BAR() __builtin_amdgcn_s_barrier()
#define SETP(n) __builtin_amdgcn_s_setprio(n)

// read A quadrant q (rows q*64.. of this wave's wr-half) from dbuf DB
#define RD_A(DB, q) do { \
  _Pragma("unroll") \
  for (int i_ = 0; i_ < 4; ++i_) { \
    aF[i_][0] = *reinterpret_cast<const bf16x8*>(&ldsb[(DB) + aRd + (unsigned)((q) * 64 + i_ * 16) * 128u + ks0]); \
    aF[i_][1] = *reinterpret_cast<const bf16x8*>(&ldsb[(DB) + aRd + (unsigned)((q) * 64 + i_ * 16) * 128u + ks1]); \
  } \
} while (0)

// read B n-half nh (cols nh*32.. of this wave's 64-col strip) from dbuf DB
#define RD_B(DB, nh, BF) do { \
  _Pragma("unroll") \
  for (int j_ = 0; j_ < 2; ++j_) { \
    BF[j_][0] = *reinterpret_cast<const bf16x8*>(&ldsb[(DB) + bRd + (unsigned)((nh) * 32 + j_ * 16) * 128u + ks0]); \
    BF[j_][1] = *reinterpret_cast<const bf16x8*>(&ldsb[(DB) + bRd + (unsigned)((nh) * 32 + j_ * 16) * 128u + ks1]); \
  } \
} while (0)

// stage one 16KB half-tile (tile index tau): 2 global_load_lds per thread
#define STG(BASE, P, tau) do { \
  __builtin_amdgcn_global_load_lds((const gmem_byte*)((P) + (size_t)(tau) * 64), \
                                   (lds_byte*)&ldsb[(BASE) + wOff], 16, 0, 0); \
  __builtin_amdgcn_global_load_lds((const gmem_byte*)((P) + (size_t)64 * K + (size_t)(tau) * 64), \
                                   (lds_byte*)&ldsb[(BASE) + 8192u + wOff], 16, 0, 0); \
} while (0)

// 16 MFMA: C-quadrant (q, nh) x K=64 (s=0,1)
#define MMQ(q, nh, BF) do { \
  _Pragma("unroll") \
  for (int i_ = 0; i_ < 4; ++i_) \
  _Pragma("unroll") \
  for (int j_ = 0; j_ < 2; ++j_) { \
    acc[(q) * 4 + i_][(nh) * 2 + j_] = __builtin_amdgcn_mfma_f32_16x16x32_bf16(aF[i_][0], BF[j_][0], acc[(q) * 4 + i_][(nh) * 2 + j_], 0, 0, 0); \
    acc[(q) * 4 + i_][(nh) * 2 + j_] = __builtin_amdgcn_mfma_f32_16x16x32_bf16(aF[i_][1], BF[j_][1], acc[(q) * 4 + i_][(nh) * 2 + j_], 0, 0, 0); \
  } \
} while (0)

__launch_bounds__(512, 2)
__global__ void gemm256_kernel(const bf16_t* __restrict__ A, const bf16_t* __restrict__ B,
                               const float* __restrict__ bias, float* __restrict__ C,
                               int M, int N, int K) {
  __shared__ __align__(16) unsigned char ldsb[131072];

  const int tid = threadIdx.x;
  const int lane = tid & 63;
  const int w = tid >> 6;       // 0..7
  const int wr = w >> 2;        // m-half
  const int wc = w & 3;         // n-quarter

  // T1: bijective XCD swizzle (MT % 8 == 0 path).
  const int MT = M >> 8;
  int mt, nt;
  const int bid = blockIdx.x;
  if ((MT & 7) == 0) {
    const int xcd = bid & 7, idx = bid >> 3;
    const int mpx = MT >> 3;
    nt = idx / mpx;
    mt = xcd * mpx + (idx - nt * mpx);
  } else {
    mt = bid % MT;
    nt = bid / MT;
  }
  const int m0 = mt << 8, n0 = nt << 8;

  // ---- staging addressing (linear LDS dest, pre-swizzled global source) ----
  const int srow8 = lane >> 3;
  const int scol16 = (lane & 7) ^ (srow8 & 7);
  const bf16_t* aP0 = A + (size_t)(m0 + w * 8 + srow8) * K + scol16 * 8;
  const bf16_t* aP1 = aP0 + (size_t)128 * K;
  const bf16_t* bP0 = B + (size_t)(n0 + w * 8 + srow8) * K + scol16 * 8;
  const bf16_t* bP1 = bP0 + (size_t)128 * K;
  const unsigned wOff = (unsigned)w * 1024u;

  // ---- fragment read addressing (swizzle folded, lane-constant) ----
  const unsigned fr = lane & 15;
  const unsigned hi16 = (unsigned)lane >> 4;
  const unsigned sw = (fr & 7u) << 4;
  const unsigned ks0 = (hi16 * 16u) ^ sw;          // k 0..31 chunk
  const unsigned ks1 = (64u + hi16 * 16u) ^ sw;    // k 32..63 chunk
  const unsigned aRd = (unsigned)wr * 16384u + fr * 128u;
  const unsigned bRd = 32768u + (unsigned)(wc >> 1) * 16384u +
                       ((unsigned)(wc & 1) * 64u + fr) * 128u;

  f32x4 acc[8][4];
  const f32x4 zero = {0.f, 0.f, 0.f, 0.f};
#pragma unroll
  for (int i = 0; i < 8; ++i)
#pragma unroll
    for (int j = 0; j < 4; ++j) acc[i][j] = zero;

  bf16x8 aF[4][2], bF0[2][2], bF1[2][2];

  const int NITER = K >> 7;  // >= 2 guarded at launch

  // ---- prologue: d0 = tile0 {A0,B0,B1,A1}; d1 = tile1 {B0,B1,A0} ----
  STG(0u, aP0, 0); STG(32768u, bP0, 0); STG(49152u, bP1, 0); STG(16384u, aP1, 0);
  STG(98304u, bP0, 1); STG(114688u, bP1, 1); STG(65536u, aP0, 1);
  WAITV(6);  // tile0's 8 loads landed; carry = 6 (d1 B0,B1,A0)
  BAR();     // published
  RD_B(0u, 0, bF0); RD_B(0u, 1, bF1); RD_A(0u, 0);   // phase-1 operands, 1 phase early

  for (int it = 0; it < NITER - 1; ++it) {
    const int t = 2 * it;
    // p1: MFMA d0(q0,n0); stage d1.A1(t+1)
    STG(81920u, aP1, t + 1);
    WAITL(0);
    SETP(1); MMQ(0, 0, bF0); SETP(0);
    BAR();
    // p2: MFMA d0(q0,n1); stage d0.B0(t+2); bottom: read Aq1(d0) (aF dead)
    STG(32768u, bP0, t + 2);
    SETP(1); MMQ(0, 1, bF1); SETP(0);
    RD_A(0u, 1);
    BAR();
    // p3: MFMA d0(q1,n0); stage d0.B1(t+2)
    STG(49152u, bP1, t + 2);
    WAITL(0);
    SETP(1); MMQ(1, 0, bF0); SETP(0);
    BAR();
    // p4: publish d1(t+1); stage d0.A0(t+2); MFMA d0(q1,n1); read d1 ops
    WAITV(4);
    BAR();
    STG(0u, aP0, t + 2);
    SETP(1); MMQ(1, 1, bF1); SETP(0);
    RD_B(65536u, 0, bF0); RD_B(65536u, 1, bF1); RD_A(65536u, 0);
    // (no end barrier: next overwrites guarded by p3/p5 barriers)
    // p5: MFMA d1(q0,n0); stage d0.A1(t+2)
    STG(16384u, aP1, t + 2);
    WAITL(0);
    SETP(1); MMQ(0, 0, bF0); SETP(0);
    BAR();
    // p6: MFMA d1(q0,n1); stage d1.B0(t+3); bottom: read Aq1(d1)
    STG(98304u, bP0, t + 3);
    SETP(1); MMQ(0, 1, bF1); SETP(0);
    RD_A(65536u, 1);
    BAR();
    // p7: MFMA d1(q1,n0); stage d1.B1(t+3)
    STG(114688u, bP1, t + 3);
    WAITL(0);
    SETP(1); MMQ(1, 0, bF0); SETP(0);
    BAR();
    // p8: publish d0(t+2); stage d1.A0(t+3); MFMA d1(q1,n1); read d0(t+2) ops
    WAITV(4);
    BAR();
    STG(65536u, aP0, t + 3);
    SETP(1); MMQ(1, 1, bF1); SETP(0);
    RD_B(0u, 0, bF0); RD_B(0u, 1, bF1); RD_A(0u, 0);
    // (no end barrier: p1's STG guarded by p7-drain + p8-mid BAR)
  }
  // ---- tail iteration (t = 2*NITER-2): only p1's stage; WAITV(0) at p4 ----
  {
    const int t = 2 * NITER - 2;
    STG(81920u, aP1, t + 1);
    WAITL(0);
    SETP(1); MMQ(0, 0, bF0); SETP(0);
    BAR();
    SETP(1); MMQ(0, 1, bF1); SETP(0);
    RD_A(0u, 1);
    BAR();
    WAITL(0);
    SETP(1); MMQ(1, 0, bF0); SETP(0);
    BAR();
    WAITV(0);   // d1(t+1) fully landed; no further LDS writes
    BAR();
    SETP(1); MMQ(1, 1, bF1); SETP(0);
    RD_B(65536u, 0, bF0); RD_B(65536u, 1, bF1); RD_A(65536u, 0);
    WAITL(0);
    SETP(1); MMQ(0, 0, bF0); SETP(0);
    SETP(1); MMQ(0, 1, bF1); SETP(0);
    RD_A(65536u, 1);
    WAITL(0);
    SETP(1); MMQ(1, 0, bF0); SETP(0);
    SETP(1); MMQ(1, 1, bF1); SETP(0);
  }

  // epilogue: C/D layout col = lane&15 (n), row = (lane>>4)*4 + r (m)
  const int row0 = m0 + wr * 128 + ((lane >> 4) << 2);
  const int col0 = n0 + wc * 64 + (lane & 15);
#pragma unroll
  for (int j = 0; j < 4; ++j) {
    const int n = col0 + j * 16;
    const float bv = bias[n];
#pragma unroll
    for (int hi = 0; hi < 8; ++hi) {
      const int rbase = row0 + (hi >> 2) * 64 + (hi & 3) * 16;
#pragma unroll
      for (int r = 0; r < 4; ++r)
        C[(size_t)(rbase + r) * N + n] = acc[hi][j][r] + bv;
    }
  }
}

// ---------------- fallback: 128x128 kernel (non-conforming shapes) ----------------
#define BM 128
#define BK 32
__launch_bounds__(256)
__global__ void gemm_bt_kernel(const bf16_t* __restrict__ A, const bf16_t* __restrict__ B,
                               const float* __restrict__ bias, float* __restrict__ C,
                               int M, int N, int K) {
  __shared__ __align__(16) bf16_t As[2][BM * BK];
  __shared__ __align__(16) bf16_t Bs[2][BM * BK];
  const int tid = threadIdx.x;
  const int lane = tid & 63;
  const int w = tid >> 6;
  const int wr = w >> 1;
  const int wc = w & 1;
  const int m0 = blockIdx.y * BM;
  const int n0 = blockIdx.x * BM;
  const int srow = lane >> 2;
  const int schunk = lane & 3;
  f32x4 acc[4][4];
  const f32x4 zero = {0.f, 0.f, 0.f, 0.f};
#pragma unroll
  for (int i = 0; i < 4; ++i)
#pragma unroll
    for (int j = 0; j < 4; ++j) acc[i][j] = zero;
  const int nt = K / BK;
  auto stage = [&](int t, int buf) {
    const int k0 = t * BK;
#pragma unroll
    for (int j = 0; j < 2; ++j) {
      const int row = w * 32 + j * 16;
      const bf16_t* ga = A + (size_t)(m0 + row + srow) * K + k0 + schunk * 8;
      __builtin_amdgcn_global_load_lds((const gmem_byte*)ga, (lds_byte*)&As[buf][row * BK], 16, 0, 0);
      const bf16_t* gb = B + (size_t)(n0 + row + srow) * K + k0 + schunk * 8;
      __builtin_amdgcn_global_load_lds((const gmem_byte*)gb, (lds_byte*)&Bs[buf][row * BK], 16, 0, 0);
    }
  };
  auto compute = [&](int buf) {
    bf16x8 af[4], bfr[4];
    const int fr2 = lane & 15;
    const int kc = (lane >> 4) * 8;
#pragma unroll
    for (int i = 0; i < 4; ++i) {
      af[i] = *reinterpret_cast<const bf16x8*>(&As[buf][(wr * 64 + i * 16 + fr2) * BK + kc]);
      bfr[i] = *reinterpret_cast<const bf16x8*>(&Bs[buf][(wc * 64 + i * 16 + fr2) * BK + kc]);
    }
#pragma unroll
    for (int i = 0; i < 4; ++i)
#pragma unroll
      for (int j = 0; j < 4; ++j)
        acc[i][j] = __builtin_amdgcn_mfma_f32_16x16x32_bf16(af[i], bfr[j], acc[i][j], 0, 0, 0);
  };
  stage(0, 0);
  __syncthreads();
  int cur = 0;
  for (int t = 0; t < nt - 1; ++t) {
    stage(t + 1, cur ^ 1);
    compute(cur);
    __syncthreads();
    cur ^= 1;
  }
  compute(cur);
#pragma unroll
  for (int j = 0; j < 4; ++j) {
    const int n = n0 + wc * 64 + j * 16 + (lane & 15);
    const float bv = bias[n];
#pragma unroll
    for (int i = 0; i < 4; ++i) {
      const int mbase = m0 + wr * 64 + i * 16 + (lane >> 4) * 4;
#pragma unroll
      for (int r = 0; r < 4; ++r)
        C[(size_t)(mbase + r) * N + n] = acc[i][j][r] + bv;
    }
  }
}

extern "C" void kernel_launch(void* const* d_in, const int* in_sizes, int n_in,
                              void* d_out, int out_size, void* d_ws, size_t ws_size,
                              hipStream_t stream) {
  const float* x = (const float*)d_in[0];
  const int* qw = (const int*)d_in[1];
  const float* sc = (const float*)d_in[2];
  const float* bias = (const float*)d_in[3];
  float* out = (float*)d_out;

  const long O = in_sizes[3];
  const long I = in_sizes[1] / O;        // 4096
  const long M = in_sizes[0] / I;        // 8192
  const long G = I / (in_sizes[2] / O);  // 128

  bf16_t* xb = (bf16_t*)d_ws;
  bf16_t* wb = xb + (size_t)M * I;
  const size_t need = ((size_t)M * I + (size_t)O * I) * sizeof(bf16_t);
  if (ws_size < need) return;

  cvt_x_kernel<<<2048, 256, 0, stream>>>(x, xb, M * I / 8);

  dim3 dgrid((unsigned)((I / 8 + 255) / 256), (unsigned)O);
  deq_w_kernel<<<dgrid, 256, 0, stream>>>(qw, sc, wb, (int)I, (int)G);

  if ((M & 255) == 0 && (O & 255) == 0 && (I & 127) == 0 && I >= 256) {
    const int nwg = (int)((M >> 8) * (O >> 8));
    gemm256_kernel<<<nwg, 512, 0, stream>>>(xb, wb, bias, out, (int)M, (int)O, (int)I);
  } else {
    dim3 ggrid((unsigned)(O / BM), (unsigned)(M / BM));
    gemm_bt_kernel<<<ggrid, 256, 0, stream>>>(xb, wb, bias, out, (int)M, (int)O, (int)I);
  }
}

// Round 8
// 867.847 us; speedup vs baseline: 1.1119x; 1.1119x over previous
//
#include <hip/hip_runtime.h>
#include <hip/hip_bf16.h>

// QuantizedLinear: y[M,N] = x[M,K] . W[N,K]^T + bias ; W = int4 * groupscale(G=128)
// Round 7: R5's verified 8-phase skeleton (barriers/waits/staging identical),
// MFMA shape switched to 32x32x16 bf16 (2495 vs 2176 TF ceiling, half the
// instruction count). Frag/epilogue/addressing updated; schedule untouched.

typedef __bf16 bf16_t;
typedef __bf16 bf16x8 __attribute__((ext_vector_type(8)));
typedef float f32x16 __attribute__((ext_vector_type(16)));
typedef float f32x4 __attribute__((ext_vector_type(4)));
typedef __attribute__((address_space(3))) unsigned char lds_byte;
typedef __attribute__((address_space(1))) unsigned char gmem_byte;

// ---------------- pre-pass 1: x fp32 -> bf16 ----------------
__global__ void cvt_x_kernel(const float* __restrict__ x, bf16_t* __restrict__ xb, long n8) {
  const long stride = (long)gridDim.x * blockDim.x;
  for (long i = (long)blockIdx.x * blockDim.x + threadIdx.x; i < n8; i += stride) {
    const float4* p = reinterpret_cast<const float4*>(x + i * 8);
    const float4 f0 = p[0];
    const float4 f1 = p[1];
    bf16x8 o;
    o[0] = (bf16_t)f0.x; o[1] = (bf16_t)f0.y; o[2] = (bf16_t)f0.z; o[3] = (bf16_t)f0.w;
    o[4] = (bf16_t)f1.x; o[5] = (bf16_t)f1.y; o[6] = (bf16_t)f1.z; o[7] = (bf16_t)f1.w;
    *reinterpret_cast<bf16x8*>(xb + i * 8) = o;
  }
}

// ---------------- pre-pass 2: W int32(int4) * scale -> bf16 ----------------
__global__ void deq_w_kernel(const int* __restrict__ qw, const float* __restrict__ sc,
                             bf16_t* __restrict__ wb, int I, int G) {
  const int n = blockIdx.y;
  const int kb = blockIdx.x * blockDim.x + threadIdx.x;
  const int k = kb * 8;
  if (k >= I) return;
  const float s = sc[(size_t)n * (I / G) + k / G];
  const int4* qp = reinterpret_cast<const int4*>(qw + (size_t)n * I + k);
  const int4 q0 = qp[0];
  const int4 q1 = qp[1];
  bf16x8 o;
  o[0] = (bf16_t)((float)q0.x * s);
  o[1] = (bf16_t)((float)q0.y * s);
  o[2] = (bf16_t)((float)q0.z * s);
  o[3] = (bf16_t)((float)q0.w * s);
  o[4] = (bf16_t)((float)q1.x * s);
  o[5] = (bf16_t)((float)q1.y * s);
  o[6] = (bf16_t)((float)q1.z * s);
  o[7] = (bf16_t)((float)q1.w * s);
  *reinterpret_cast<bf16x8*>(wb + (size_t)n * I + k) = o;
}

// =================== 256x256 8-wave 8-phase GEMM (32x32x16 MFMA) ===================
// LDS 128KB: dbuf d0 @0 / d1 @+64K; halves A0(+0) A1(+16K) B0(+32K) B1(+48K).
// Half = 128 rows x 64 k bf16, 128B rows; XOR swizzle 16B-slot ^= (row&7)
// (write: linear LDS dest + pre-permuted global source col; read: lane-const).
// Wave out 128x64 = 4 m-tiles x 2 n-tiles of 32x32. Phase (q,nh): m-tiles
// {2q,2q+1} x n-tile nh x 4 k-steps = 8 MFMA. Same phase->LDS-region map as
// R5, so R5's verified stage/read hazard table applies unchanged.

#define WAITV(n) asm volatile("s_waitcnt vmcnt(" #n ")" ::: "memory")
#define WAITL(n) asm volatile("s_waitcnt lgkmcnt(" #n ")" ::: "memory")
#define BAR() __builtin_amdgcn_s_barrier()
#define SETP(n) __builtin_amdgcn_s_setprio(n)

// read A quadrant q (2 m-tiles x 4 k-steps) from dbuf DB -> aF[2][4]
#define RD_A(DB, q) do { \
  _Pragma("unroll") \
  for (int mt_ = 0; mt_ < 2; ++mt_) \
  _Pragma("unroll") \
  for (int kk_ = 0; kk_ < 4; ++kk_) \
    aF[mt_][kk_] = *reinterpret_cast<const bf16x8*>( \
      &ldsb[(DB) + aRd + (unsigned)(q) * 8192u + (unsigned)mt_ * 4096u + ((unsigned)(kk_ * 32) ^ kbase)]); \
} while (0)

// read B n-tile nh (4 k-steps) from dbuf DB -> BF[4]
#define RD_B(DB, nh, BF) do { \
  _Pragma("unroll") \
  for (int kk_ = 0; kk_ < 4; ++kk_) \
    BF[kk_] = *reinterpret_cast<const bf16x8*>( \
      &ldsb[(DB) + bRd + (unsigned)(nh) * 4096u + ((unsigned)(kk_ * 32) ^ kbase)]); \
} while (0)

// stage one 16KB half-tile (tile index tau): 2 global_load_lds per thread
#define STG(BASE, P, tau) do { \
  __builtin_amdgcn_global_load_lds((const gmem_byte*)((P) + (size_t)(tau) * 64), \
                                   (lds_byte*)&ldsb[(BASE) + wOff], 16, 0, 0); \
  __builtin_amdgcn_global_load_lds((const gmem_byte*)((P) + (size_t)64 * K + (size_t)(tau) * 64), \
                                   (lds_byte*)&ldsb[(BASE) + 8192u + wOff], 16, 0, 0); \
} while (0)

// 8 MFMA: m-tiles {2q,2q+1} x n-tile nh x K=64
#define MMQ(q, nh, BF) do { \
  _Pragma("unroll") \
  for (int kk_ = 0; kk_ < 4; ++kk_) { \
    acc[((q) * 2 + 0) * 2 + (nh)] = __builtin_amdgcn_mfma_f32_32x32x16_bf16(aF[0][kk_], BF[kk_], acc[((q) * 2 + 0) * 2 + (nh)], 0, 0, 0); \
    acc[((q) * 2 + 1) * 2 + (nh)] = __builtin_amdgcn_mfma_f32_32x32x16_bf16(aF[1][kk_], BF[kk_], acc[((q) * 2 + 1) * 2 + (nh)], 0, 0, 0); \
  } \
} while (0)

__launch_bounds__(512, 2)
__global__ void gemm256_kernel(const bf16_t* __restrict__ A, const bf16_t* __restrict__ B,
                               const float* __restrict__ bias, float* __restrict__ C,
                               int M, int N, int K) {
  __shared__ __align__(16) unsigned char ldsb[131072];

  const int tid = threadIdx.x;
  const int lane = tid & 63;
  const int w = tid >> 6;       // 0..7
  const int wr = w >> 2;        // m-half
  const int wc = w & 3;         // n-quarter

  // T1: bijective XCD swizzle (MT % 8 == 0 path).
  const int MT = M >> 8;
  int mt, nt;
  const int bid = blockIdx.x;
  if ((MT & 7) == 0) {
    const int xcd = bid & 7, idx = bid >> 3;
    const int mpx = MT >> 3;
    nt = idx / mpx;
    mt = xcd * mpx + (idx - nt * mpx);
  } else {
    mt = bid % MT;
    nt = bid / MT;
  }
  const int m0 = mt << 8, n0 = nt << 8;

  // ---- staging addressing (linear LDS dest, pre-swizzled global source) ----
  const int srow8 = lane >> 3;
  const int scol16 = (lane & 7) ^ (srow8 & 7);
  const bf16_t* aP0 = A + (size_t)(m0 + w * 8 + srow8) * K + scol16 * 8;
  const bf16_t* aP1 = aP0 + (size_t)128 * K;
  const bf16_t* bP0 = B + (size_t)(n0 + w * 8 + srow8) * K + scol16 * 8;
  const bf16_t* bP1 = bP0 + (size_t)128 * K;
  const unsigned wOff = (unsigned)w * 1024u;

  // ---- fragment read addressing (32x32 frags; swizzle folded, lane-const) ----
  // A row = lane&31 (within tile), k-octet = lane>>5; same for B cols.
  const unsigned la31 = (unsigned)lane & 31u;
  const unsigned kbase = (((unsigned)lane >> 5) * 16u) ^ (((unsigned)lane & 7u) << 4);
  const unsigned aRd = (unsigned)wr * 16384u + la31 * 128u;      // + q*8192 + mt*4096
  const unsigned bRd = 32768u + (unsigned)(wc >> 1) * 16384u +
                       ((unsigned)(wc & 1) * 64u + la31) * 128u; // + nh*4096

  f32x16 acc[8];  // tile (mi 0..3, ni 0..1) -> acc[mi*2+ni]
#pragma unroll
  for (int i = 0; i < 8; ++i)
#pragma unroll
    for (int j = 0; j < 16; ++j) acc[i][j] = 0.f;

  bf16x8 aF[2][4], bF0[4], bF1[4];

  const int NITER = K >> 7;  // >= 2 guarded at launch

  // ---- prologue: d0 = tile0 {A0,B0,B1,A1}; d1 = tile1 {B0,B1,A0} ----
  STG(0u, aP0, 0); STG(32768u, bP0, 0); STG(49152u, bP1, 0); STG(16384u, aP1, 0);
  STG(98304u, bP0, 1); STG(114688u, bP1, 1); STG(65536u, aP0, 1);
  WAITV(6);  // tile0's 8 loads landed; carry = 6 (d1 B0,B1,A0)
  BAR();     // published

  for (int it = 0; it < NITER - 1; ++it) {
    const int t = 2 * it;
    // p1: read d0 Aq0 + B both; stage d1.A1(t+1); MM d0(q0,n0)
    RD_A(0u, 0); RD_B(0u, 0, bF0); RD_B(0u, 1, bF1); STG(81920u, aP1, t + 1);
    BAR(); WAITL(0);
    SETP(1); MMQ(0, 0, bF0); SETP(0); BAR();
    // p2: MM d0(q0,n1); stage d0.B0(t+2)  [d0.B last read: p1]
    STG(32768u, bP0, t + 2);
    BAR();
    SETP(1); MMQ(0, 1, bF1); SETP(0); BAR();
    // p3: read d0 Aq1; stage d0.B1(t+2); MM d0(q1,n0)
    RD_A(0u, 1); STG(49152u, bP1, t + 2);
    BAR(); WAITL(0);
    SETP(1); MMQ(1, 0, bF0); SETP(0); BAR();
    // p4: stage d0.A0(t+2) [d0.A last read: p3]; publish tile t+1; MM d0(q1,n1)
    STG(0u, aP0, t + 2); WAITV(6);
    BAR();
    SETP(1); MMQ(1, 1, bF1); SETP(0); BAR();
    // p5: read d1 Aq0 + B both; stage d0.A1(t+2); MM d1(q0,n0)
    RD_A(65536u, 0); RD_B(65536u, 0, bF0); RD_B(65536u, 1, bF1); STG(16384u, aP1, t + 2);
    BAR(); WAITL(0);
    SETP(1); MMQ(0, 0, bF0); SETP(0); BAR();
    // p6: MM d1(q0,n1); stage d1.B0(t+3)  [d1.B last read: p5]
    STG(98304u, bP0, t + 3);
    BAR();
    SETP(1); MMQ(0, 1, bF1); SETP(0); BAR();
    // p7: read d1 Aq1; stage d1.B1(t+3); MM d1(q1,n0)
    RD_A(65536u, 1); STG(114688u, bP1, t + 3);
    BAR(); WAITL(0);
    SETP(1); MMQ(1, 0, bF0); SETP(0); BAR();
    // p8: stage d1.A0(t+3) [d1.A last read: p7]; publish d0 tile t+2; MM d1(q1,n1)
    STG(65536u, aP0, t + 3); WAITV(6);
    BAR();
    SETP(1); MMQ(1, 1, bF1); SETP(0); BAR();
  }
  // ---- last iteration (t = 2*NITER-2): only p1's stage; drain at p4 ----
  {
    const int t = 2 * NITER - 2;
    RD_A(0u, 0); RD_B(0u, 0, bF0); RD_B(0u, 1, bF1); STG(81920u, aP1, t + 1);
    BAR(); WAITL(0);
    SETP(1); MMQ(0, 0, bF0); SETP(0); BAR();
    BAR();
    SETP(1); MMQ(0, 1, bF1); SETP(0); BAR();
    RD_A(0u, 1);
    BAR(); WAITL(0);
    SETP(1); MMQ(1, 0, bF0); SETP(0); BAR();
    WAITV(0);   // drain carry-in d1 halves + p1's A1 stage
    BAR();
    SETP(1); MMQ(1, 1, bF1); SETP(0); BAR();
    // d1 tile t+1 fully resident & published; no further LDS writes anywhere.
    RD_A(65536u, 0); RD_B(65536u, 0, bF0); RD_B(65536u, 1, bF1);
    WAITL(0);
    SETP(1); MMQ(0, 0, bF0); SETP(0);
    SETP(1); MMQ(0, 1, bF1); SETP(0);
    RD_A(65536u, 1);
    WAITL(0);
    SETP(1); MMQ(1, 0, bF0); SETP(0);
    SETP(1); MMQ(1, 1, bF1); SETP(0);
  }

  // epilogue: 32x32 C/D layout col = lane&31, row = (reg&3) + 8*(reg>>2) + 4*(lane>>5)
  const int row0 = m0 + wr * 128 + (((int)lane >> 5) << 2);
  const int col0 = n0 + wc * 64 + (int)la31;
#pragma unroll
  for (int ni = 0; ni < 2; ++ni) {
    const int n = col0 + ni * 32;
    const float bv = bias[n];
#pragma unroll
    for (int mi = 0; mi < 4; ++mi) {
      const f32x16 t = acc[mi * 2 + ni];
#pragma unroll
      for (int r = 0; r < 16; ++r) {
        const int row = row0 + mi * 32 + (r & 3) + ((r >> 2) << 3);
        C[(size_t)row * N + n] = t[r] + bv;
      }
    }
  }
}

// ---------------- fallback: 128x128 kernel (non-conforming shapes) ----------------
#define BM 128
#define BK 32
__launch_bounds__(256)
__global__ void gemm_bt_kernel(const bf16_t* __restrict__ A, const bf16_t* __restrict__ B,
                               const float* __restrict__ bias, float* __restrict__ C,
                               int M, int N, int K) {
  __shared__ __align__(16) bf16_t As[2][BM * BK];
  __shared__ __align__(16) bf16_t Bs[2][BM * BK];
  const int tid = threadIdx.x;
  const int lane = tid & 63;
  const int w = tid >> 6;
  const int wr = w >> 1;
  const int wc = w & 1;
  const int m0 = blockIdx.y * BM;
  const int n0 = blockIdx.x * BM;
  const int srow = lane >> 2;
  const int schunk = lane & 3;
  f32x4 acc[4][4];
  const f32x4 zero = {0.f, 0.f, 0.f, 0.f};
#pragma unroll
  for (int i = 0; i < 4; ++i)
#pragma unroll
    for (int j = 0; j < 4; ++j) acc[i][j] = zero;
  const int nt = K / BK;
  auto stage = [&](int t, int buf) {
    const int k0 = t * BK;
#pragma unroll
    for (int j = 0; j < 2; ++j) {
      const int row = w * 32 + j * 16;
      const bf16_t* ga = A + (size_t)(m0 + row + srow) * K + k0 + schunk * 8;
      __builtin_amdgcn_global_load_lds((const gmem_byte*)ga, (lds_byte*)&As[buf][row * BK], 16, 0, 0);
      const bf16_t* gb = B + (size_t)(n0 + row + srow) * K + k0 + schunk * 8;
      __builtin_amdgcn_global_load_lds((const gmem_byte*)gb, (lds_byte*)&Bs[buf][row * BK], 16, 0, 0);
    }
  };
  auto compute = [&](int buf) {
    bf16x8 af[4], bfr[4];
    const int fr2 = lane & 15;
    const int kc = (lane >> 4) * 8;
#pragma unroll
    for (int i = 0; i < 4; ++i) {
      af[i] = *reinterpret_cast<const bf16x8*>(&As[buf][(wr * 64 + i * 16 + fr2) * BK + kc]);
      bfr[i] = *reinterpret_cast<const bf16x8*>(&Bs[buf][(wc * 64 + i * 16 + fr2) * BK + kc]);
    }
#pragma unroll
    for (int i = 0; i < 4; ++i)
#pragma unroll
      for (int j = 0; j < 4; ++j)
        acc[i][j] = __builtin_amdgcn_mfma_f32_16x16x32_bf16(af[i], bfr[j], acc[i][j], 0, 0, 0);
  };
  stage(0, 0);
  __syncthreads();
  int cur = 0;
  for (int t = 0; t < nt - 1; ++t) {
    stage(t + 1, cur ^ 1);
    compute(cur);
    __syncthreads();
    cur ^= 1;
  }
  compute(cur);
#pragma unroll
  for (int j = 0; j < 4; ++j) {
    const int n = n0 + wc * 64 + j * 16 + (lane & 15);
    const float bv = bias[n];
#pragma unroll
    for (int i = 0; i < 4; ++i) {
      const int mbase = m0 + wr * 64 + i * 16 + (lane >> 4) * 4;
#pragma unroll
      for (int r = 0; r < 4; ++r)
        C[(size_t)(mbase + r) * N + n] = acc[i][j][r] + bv;
    }
  }
}

extern "C" void kernel_launch(void* const* d_in, const int* in_sizes, int n_in,
                              void* d_out, int out_size, void* d_ws, size_t ws_size,
                              hipStream_t stream) {
  const float* x = (const float*)d_in[0];
  const int* qw = (const int*)d_in[1];
  const float* sc = (const float*)d_in[2];
  const float* bias = (const float*)d_in[3];
  float* out = (float*)d_out;

  const long O = in_sizes[3];
  const long I = in_sizes[1] / O;        // 4096
  const long M = in_sizes[0] / I;        // 8192
  const long G = I / (in_sizes[2] / O);  // 128

  bf16_t* xb = (bf16_t*)d_ws;
  bf16_t* wb = xb + (size_t)M * I;
  const size_t need = ((size_t)M * I + (size_t)O * I) * sizeof(bf16_t);
  if (ws_size < need) return;

  cvt_x_kernel<<<2048, 256, 0, stream>>>(x, xb, M * I / 8);

  dim3 dgrid((unsigned)((I / 8 + 255) / 256), (unsigned)O);
  deq_w_kernel<<<dgrid, 256, 0, stream>>>(qw, sc, wb, (int)I, (int)G);

  if ((M & 255) == 0 && (O & 255) == 0 && (I & 127) == 0 && I >= 256) {
    const int nwg = (int)((M >> 8) * (O >> 8));
    gemm256_kernel<<<nwg, 512, 0, stream>>>(xb, wb, bias, out, (int)M, (int)O, (int)I);
  } else {
    dim3 ggrid((unsigned)(O / BM), (unsigned)(M / BM));
    gemm_bt_kernel<<<ggrid, 256, 0, stream>>>(xb, wb, bias, out, (int)M, (int)O, (int)I);
  }
}